// Round 1
// baseline (88.170 us; speedup 1.0000x reference)
//
#include <hip/hip_runtime.h>

// AFM: B=4096, N=32, M=64, P = N*(N-1)/2 = 496.
// Key simplifications (exact in math, fp32-rounding-level differences only):
//  1) softmax over a size-1 axis == 1.0 -> attention is identity; fAtt = mean_p(fPI).
//  2) sum_{i<j} x_i*x_j = ((sum x)^2 - sum x^2)/2  (FM trick), with x[n,m] = dense[b,n,m]*v[n,m].
// out[b] = (sum_n dense[b,n,0]*Wl[n] + bl) + (sum_m ((S1_m^2 - S2_m)/(2P))*Wp[m] + bp)

constexpr int Bx = 4096;
constexpr int Nx = 32;
constexpr int Mx = 64;
constexpr int Px = (Nx * (Nx - 1)) / 2; // 496

__global__ __launch_bounds__(256) void afm_kernel(
    const float* __restrict__ dense,  // (B, N, M)
    const float* __restrict__ Wl,     // (N, 1)
    const float* __restrict__ bl,     // (1,)
    const float* __restrict__ v,      // (N, M)
    const float* __restrict__ Wp,     // (M, 1)
    const float* __restrict__ bp,     // (1,)
    float* __restrict__ out)          // (B, 1)
{
    const int wave = threadIdx.x >> 6;          // 0..3 within block
    const int lane = threadIdx.x & 63;
    const int b    = blockIdx.x * 4 + wave;     // grid = B/4 blocks exactly

    const int q  = lane >> 4;   // row partition: rows n = q + 4*i, i=0..7
    const int mq = lane & 15;   // m-quad: columns m = 4*mq .. 4*mq+3

    const float4* __restrict__ dv  = reinterpret_cast<const float4*>(dense + (size_t)b * (Nx * Mx));
    const float4* __restrict__ vv4 = reinterpret_cast<const float4*>(v);

    float s1[4] = {0.f, 0.f, 0.f, 0.f};
    float s2[4] = {0.f, 0.f, 0.f, 0.f};
    float lin = 0.f;

#pragma unroll
    for (int i = 0; i < 8; ++i) {
        const int n = q + 4 * i;                 // row index 0..31
        const float4 d = dv[n * 16 + mq];        // 16B/lane, wave covers 1KiB contiguous
        const float4 w = vv4[n * 16 + mq];       // L1-resident (8 KiB total)
        if (mq == 0) lin += d.x * Wl[n];         // sparse column = dense[:, :, 0]
        const float x0 = d.x * w.x;
        const float x1 = d.y * w.y;
        const float x2 = d.z * w.z;
        const float x3 = d.w * w.w;
        s1[0] += x0; s2[0] += x0 * x0;
        s1[1] += x1; s2[1] += x1 * x1;
        s1[2] += x2; s2[2] += x2 * x2;
        s1[3] += x3; s2[3] += x3 * x3;
    }

    // Fold the 4 row-partitions together: xor 16 and 32 (lanes sharing mq).
#pragma unroll
    for (int off = 16; off <= 32; off <<= 1) {
#pragma unroll
        for (int k = 0; k < 4; ++k) {
            s1[k] += __shfl_xor(s1[k], off, 64);
            s2[k] += __shfl_xor(s2[k], off, 64);
        }
        lin += __shfl_xor(lin, off, 64);
    }

    // Per-lane partial of fAtt @ Wp (lanes replicated 4x across q-groups; each
    // 16-lane group independently sums the full set of mq=0..15).
    const float inv2P = 0.5f / (float)Px;
    float partial = 0.f;
#pragma unroll
    for (int k = 0; k < 4; ++k) {
        partial += (s1[k] * s1[k] - s2[k]) * (inv2P * Wp[4 * mq + k]);
    }
    if (mq == 0) partial += lin;  // exactly one mq==0 lane per 16-lane group

    // Reduce across mq within each 16-lane group (all groups identical).
#pragma unroll
    for (int off = 1; off <= 8; off <<= 1)
        partial += __shfl_xor(partial, off, 64);

    if (lane == 0) out[b] = partial + bl[0] + bp[0];
}

extern "C" void kernel_launch(void* const* d_in, const int* in_sizes, int n_in,
                              void* d_out, int out_size, void* d_ws, size_t ws_size,
                              hipStream_t stream) {
    const float* dense = (const float*)d_in[0];
    const float* Wl    = (const float*)d_in[1];
    const float* bl    = (const float*)d_in[2];
    const float* v     = (const float*)d_in[3];
    // d_in[4..7] = Wa1, ba1, Wa2, ba2 — unused: softmax over singleton axis == 1.
    const float* Wp    = (const float*)d_in[8];
    const float* bp    = (const float*)d_in[9];
    float* out = (float*)d_out;

    afm_kernel<<<Bx / 4, 256, 0, stream>>>(dense, Wl, bl, v, Wp, bp, out);
}